// Round 3
// baseline (128.423 us; speedup 1.0000x reference)
//
#include <hip/hip_runtime.h>

// dqn MLP: 8 -> 5 -> 5 -> 5 -> 5 -> 5 -> 4, fp32.
// layer0: linear only; layers 1-4: linear+relu; layer5: linear+relu.
// BATCH = 2,097,152 rows. Memory-bound streaming kernel.
//
// v3: back to direct stride-2 float4 loads (v2b's LDS redistribution was
// measured pure overhead, +6us: the 2-lanes-per-64B-line pattern already
// gets full line utilization via L1 between the two back-to-back loads).
// Non-temporal load/store on the streamed x/out (touched once; poison
// fill flushes L3 each iteration anyway) to avoid cache-allocation churn.

#define IN_DIM 8
#define HID 5
#define OUT_DIM 4
#define BLOCK 256

typedef float f32x4 __attribute__((ext_vector_type(4)));

__global__ __launch_bounds__(BLOCK) void dqn_mlp_kernel(
    const float* __restrict__ x,
    const float* __restrict__ W0, const float* __restrict__ b0,
    const float* __restrict__ W1, const float* __restrict__ b1,
    const float* __restrict__ W2, const float* __restrict__ b2,
    const float* __restrict__ W3, const float* __restrict__ b3,
    const float* __restrict__ W4, const float* __restrict__ b4,
    const float* __restrict__ W5, const float* __restrict__ b5,
    float* __restrict__ out, int batch)
{
    int i = blockIdx.x * blockDim.x + threadIdx.x;
    if (i >= batch) return;

    // Load the 8-float input row as two non-temporal float4 (32B/lane).
    // Lanes are 32B apart: 2 lanes per 64B line per instruction; the two
    // instructions together fully consume each line (L1-resident).
    const f32x4* __restrict__ xv = reinterpret_cast<const f32x4*>(x);
    f32x4 xa = __builtin_nontemporal_load(xv + 2 * i);
    f32x4 xb = __builtin_nontemporal_load(xv + 2 * i + 1);
    float xin[IN_DIM] = {xa.x, xa.y, xa.z, xa.w, xb.x, xb.y, xb.z, xb.w};

    float h[HID];
    // input layer: linear only (no relu)
    #pragma unroll
    for (int j = 0; j < HID; ++j) {
        float s = b0[j];
        #pragma unroll
        for (int k = 0; k < IN_DIM; ++k) s = fmaf(xin[k], W0[j * IN_DIM + k], s);
        h[j] = s;
    }

    // hidden layers 1..4: linear + relu
    const float* __restrict__ Ws[4] = {W1, W2, W3, W4};
    const float* __restrict__ bs[4] = {b1, b2, b3, b4};
    #pragma unroll
    for (int l = 0; l < 4; ++l) {
        float g[HID];
        #pragma unroll
        for (int j = 0; j < HID; ++j) {
            float s = bs[l][j];
            #pragma unroll
            for (int k = 0; k < HID; ++k) s = fmaf(h[k], Ws[l][j * HID + k], s);
            g[j] = fmaxf(s, 0.0f);
        }
        #pragma unroll
        for (int j = 0; j < HID; ++j) h[j] = g[j];
    }

    // output layer: linear + relu
    float ov[OUT_DIM];
    #pragma unroll
    for (int j = 0; j < OUT_DIM; ++j) {
        float s = b5[j];
        #pragma unroll
        for (int k = 0; k < HID; ++k) s = fmaf(h[k], W5[j * HID + k], s);
        ov[j] = fmaxf(s, 0.0f);
    }

    // Coalesced non-temporal float4 store (output is never re-read).
    f32x4 o;
    o.x = ov[0]; o.y = ov[1]; o.z = ov[2]; o.w = ov[3];
    __builtin_nontemporal_store(o, reinterpret_cast<f32x4*>(out) + i);
}

extern "C" void kernel_launch(void* const* d_in, const int* in_sizes, int n_in,
                              void* d_out, int out_size, void* d_ws, size_t ws_size,
                              hipStream_t stream) {
    const float* x  = (const float*)d_in[0];
    const float* W0 = (const float*)d_in[1];
    const float* b0 = (const float*)d_in[2];
    const float* W1 = (const float*)d_in[3];
    const float* b1 = (const float*)d_in[4];
    const float* W2 = (const float*)d_in[5];
    const float* b2 = (const float*)d_in[6];
    const float* W3 = (const float*)d_in[7];
    const float* b3 = (const float*)d_in[8];
    const float* W4 = (const float*)d_in[9];
    const float* b4 = (const float*)d_in[10];
    const float* W5 = (const float*)d_in[11];
    const float* b5 = (const float*)d_in[12];
    float* out = (float*)d_out;

    int batch = in_sizes[0] / IN_DIM;
    int block = BLOCK;
    int grid = (batch + block - 1) / block;
    dqn_mlp_kernel<<<grid, block, 0, stream>>>(
        x, W0, b0, W1, b1, W2, b2, W3, b3, W4, b4, W5, b5, out, batch);
}

// Round 4
// 124.345 us; speedup vs baseline: 1.0328x; 1.0328x over previous
//
#include <hip/hip_runtime.h>

// dqn MLP: 8 -> 5 -> 5 -> 5 -> 5 -> 5 -> 4, fp32.
// layer0: linear only; layers 1-4: linear+relu; layer5: linear+relu.
// BATCH = 2,097,152 rows. Memory-bound streaming kernel.
//
// v4: 4 rows per thread. All 8 input float4 loads issued up-front
// (8 independent VMEM in flight), 4 independent row computations
// (4x FMA-chain ILP, uniform scalar weight loads amortized 4x),
// 4 coalesced float4 stores. No NT hints (v2b/v3 measured nt as a
// ~6-7us regression on this stream). No LDS (v2b measured overhead).

#define IN_DIM 8
#define HID 5
#define OUT_DIM 4
#define BLOCK 256
#define ROWS 4

typedef float f32x4 __attribute__((ext_vector_type(4)));

__global__ __launch_bounds__(BLOCK) void dqn_mlp_kernel(
    const float* __restrict__ x,
    const float* __restrict__ W0, const float* __restrict__ b0,
    const float* __restrict__ W1, const float* __restrict__ b1,
    const float* __restrict__ W2, const float* __restrict__ b2,
    const float* __restrict__ W3, const float* __restrict__ b3,
    const float* __restrict__ W4, const float* __restrict__ b4,
    const float* __restrict__ W5, const float* __restrict__ b5,
    float* __restrict__ out, int batch)
{
    const int t = threadIdx.x;
    // Rows handled by this thread: base + r*BLOCK + t  (r = 0..ROWS-1).
    // Consecutive lanes -> consecutive rows within each r, so every load
    // and store instruction stays coalesced.
    const int base = blockIdx.x * (BLOCK * ROWS);

    const f32x4* __restrict__ xv = reinterpret_cast<const f32x4*>(x);
    f32x4* __restrict__ ov4 = reinterpret_cast<f32x4*>(out);

    const bool full = (base + BLOCK * ROWS) <= batch;

    // ---- load phase: up to 2*ROWS independent float4 loads in flight ----
    f32x4 xa[ROWS], xb[ROWS];
    if (full) {
        #pragma unroll
        for (int r = 0; r < ROWS; ++r) {
            int row = base + r * BLOCK + t;
            xa[r] = xv[2 * row];
            xb[r] = xv[2 * row + 1];
        }
    } else {
        #pragma unroll
        for (int r = 0; r < ROWS; ++r) {
            int row = base + r * BLOCK + t;
            if (row < batch) {
                xa[r] = xv[2 * row];
                xb[r] = xv[2 * row + 1];
            }
        }
    }

    // ---- compute + store per row ----
    const float* __restrict__ Ws[4] = {W1, W2, W3, W4};
    const float* __restrict__ bs[4] = {b1, b2, b3, b4};

    #pragma unroll
    for (int r = 0; r < ROWS; ++r) {
        int row = base + r * BLOCK + t;
        if (!full && row >= batch) break;

        float xin[IN_DIM] = {xa[r].x, xa[r].y, xa[r].z, xa[r].w,
                             xb[r].x, xb[r].y, xb[r].z, xb[r].w};

        float h[HID];
        // input layer: linear only (no relu)
        #pragma unroll
        for (int j = 0; j < HID; ++j) {
            float s = b0[j];
            #pragma unroll
            for (int k = 0; k < IN_DIM; ++k) s = fmaf(xin[k], W0[j * IN_DIM + k], s);
            h[j] = s;
        }

        // hidden layers 1..4: linear + relu
        #pragma unroll
        for (int l = 0; l < 4; ++l) {
            float g[HID];
            #pragma unroll
            for (int j = 0; j < HID; ++j) {
                float s = bs[l][j];
                #pragma unroll
                for (int k = 0; k < HID; ++k) s = fmaf(h[k], Ws[l][j * HID + k], s);
                g[j] = fmaxf(s, 0.0f);
            }
            #pragma unroll
            for (int j = 0; j < HID; ++j) h[j] = g[j];
        }

        // output layer: linear + relu
        f32x4 o;
        float ovv[OUT_DIM];
        #pragma unroll
        for (int j = 0; j < OUT_DIM; ++j) {
            float s = b5[j];
            #pragma unroll
            for (int k = 0; k < HID; ++k) s = fmaf(h[k], W5[j * HID + k], s);
            ovv[j] = fmaxf(s, 0.0f);
        }
        o.x = ovv[0]; o.y = ovv[1]; o.z = ovv[2]; o.w = ovv[3];

        ov4[row] = o;
    }
}

extern "C" void kernel_launch(void* const* d_in, const int* in_sizes, int n_in,
                              void* d_out, int out_size, void* d_ws, size_t ws_size,
                              hipStream_t stream) {
    const float* x  = (const float*)d_in[0];
    const float* W0 = (const float*)d_in[1];
    const float* b0 = (const float*)d_in[2];
    const float* W1 = (const float*)d_in[3];
    const float* b1 = (const float*)d_in[4];
    const float* W2 = (const float*)d_in[5];
    const float* b2 = (const float*)d_in[6];
    const float* W3 = (const float*)d_in[7];
    const float* b3 = (const float*)d_in[8];
    const float* W4 = (const float*)d_in[9];
    const float* b4 = (const float*)d_in[10];
    const float* W5 = (const float*)d_in[11];
    const float* b5 = (const float*)d_in[12];
    float* out = (float*)d_out;

    int batch = in_sizes[0] / IN_DIM;
    int rowsPerBlock = BLOCK * ROWS;
    int grid = (batch + rowsPerBlock - 1) / rowsPerBlock;
    dqn_mlp_kernel<<<grid, BLOCK, 0, stream>>>(
        x, W0, b0, W1, b1, W2, b2, W3, b3, W4, b4, W5, b5, out, batch);
}

// Round 5
// 120.813 us; speedup vs baseline: 1.0630x; 1.0292x over previous
//
#include <hip/hip_runtime.h>

// dqn MLP: 8 -> 5 -> 5 -> 5 -> 5 -> 5 -> 4, fp32.
// layer0: linear only; layers 1-4: linear+relu; layer5: linear+relu.
// BATCH = 2,097,152 rows. Memory-bound streaming kernel:
// one thread per row, float4 in (x2), float4 out, weights via uniform
// (scalar) loads.
//
// v5 = byte-for-byte revert to the measured-best baseline (119.9/121.2us).
// Tested and rejected with counter evidence:
//   - LDS-swizzled load redistribution (+5.9us: pure overhead; the
//     stride-2-float4 pattern already gets full 64B-line utilization
//     via L1 between the two back-to-back loads)
//   - nontemporal load/store hints (+7.2us on this stream)
//   - 4 rows/thread ILP batching (+3.1us)
// Remaining dur_us is harness-owned: 41us poison fill + ~30 small
// graph-serialized dispatches per iteration.

#define IN_DIM 8
#define HID 5
#define OUT_DIM 4

__global__ __launch_bounds__(256) void dqn_mlp_kernel(
    const float* __restrict__ x,
    const float* __restrict__ W0, const float* __restrict__ b0,
    const float* __restrict__ W1, const float* __restrict__ b1,
    const float* __restrict__ W2, const float* __restrict__ b2,
    const float* __restrict__ W3, const float* __restrict__ b3,
    const float* __restrict__ W4, const float* __restrict__ b4,
    const float* __restrict__ W5, const float* __restrict__ b5,
    float* __restrict__ out, int batch)
{
    int i = blockIdx.x * blockDim.x + threadIdx.x;
    if (i >= batch) return;

    // Load the 8-float input row as two float4 (32B/lane, coalesced).
    const float4* xv = reinterpret_cast<const float4*>(x);
    float4 xa = xv[2 * i];
    float4 xb = xv[2 * i + 1];
    float xin[IN_DIM] = {xa.x, xa.y, xa.z, xa.w, xb.x, xb.y, xb.z, xb.w};

    float h[HID];
    // input layer: linear only (no relu)
    #pragma unroll
    for (int j = 0; j < HID; ++j) {
        float s = b0[j];
        #pragma unroll
        for (int k = 0; k < IN_DIM; ++k) s = fmaf(xin[k], W0[j * IN_DIM + k], s);
        h[j] = s;
    }

    // hidden layers 1..4: linear + relu
    const float* __restrict__ Ws[4] = {W1, W2, W3, W4};
    const float* __restrict__ bs[4] = {b1, b2, b3, b4};
    #pragma unroll
    for (int l = 0; l < 4; ++l) {
        float g[HID];
        #pragma unroll
        for (int j = 0; j < HID; ++j) {
            float s = bs[l][j];
            #pragma unroll
            for (int k = 0; k < HID; ++k) s = fmaf(h[k], Ws[l][j * HID + k], s);
            g[j] = fmaxf(s, 0.0f);
        }
        #pragma unroll
        for (int j = 0; j < HID; ++j) h[j] = g[j];
    }

    // output layer: linear + relu
    float ov[OUT_DIM];
    #pragma unroll
    for (int j = 0; j < OUT_DIM; ++j) {
        float s = b5[j];
        #pragma unroll
        for (int k = 0; k < HID; ++k) s = fmaf(h[k], W5[j * HID + k], s);
        ov[j] = fmaxf(s, 0.0f);
    }

    reinterpret_cast<float4*>(out)[i] = make_float4(ov[0], ov[1], ov[2], ov[3]);
}

extern "C" void kernel_launch(void* const* d_in, const int* in_sizes, int n_in,
                              void* d_out, int out_size, void* d_ws, size_t ws_size,
                              hipStream_t stream) {
    const float* x  = (const float*)d_in[0];
    const float* W0 = (const float*)d_in[1];
    const float* b0 = (const float*)d_in[2];
    const float* W1 = (const float*)d_in[3];
    const float* b1 = (const float*)d_in[4];
    const float* W2 = (const float*)d_in[5];
    const float* b2 = (const float*)d_in[6];
    const float* W3 = (const float*)d_in[7];
    const float* b3 = (const float*)d_in[8];
    const float* W4 = (const float*)d_in[9];
    const float* b4 = (const float*)d_in[10];
    const float* W5 = (const float*)d_in[11];
    const float* b5 = (const float*)d_in[12];
    float* out = (float*)d_out;

    int batch = in_sizes[0] / IN_DIM;
    int block = 256;
    int grid = (batch + block - 1) / block;
    dqn_mlp_kernel<<<grid, block, 0, stream>>>(
        x, W0, b0, W1, b1, W2, b2, W3, b3, W4, b4, W5, b5, out, batch);
}